// Round 7
// baseline (31.138 us; speedup 1.0000x reference)
//
#include <hip/hip_runtime.h>

#define NB 64
#define NS 512
#define ND 768
#define NT 4
#define NC 10
#define NEG (-1e30f)
#define LOG2E 1.4426950408889634f
#define LN2 0.6931471805599453f

// ---------------------------------------------------------------------------
// Kernel 1: fused embedding gather + projection + log_softmax.
// 1024 blocks x 256 threads; 32 tokens/block, 2 tokens per 16-lane group.
// W_eff = sW + dA[corpus] (12 KB) built in LDS per block; each weight
// ds_read_b128 now feeds 32 FMAs (2 tokens) instead of 16.
// ---------------------------------------------------------------------------
__global__ __launch_bounds__(256) void logits_kernel(
    const int* __restrict__ words, const int* __restrict__ corpus,
    const float* __restrict__ embed, const float* __restrict__ sW,
    const float* __restrict__ sb, const float* __restrict__ dA,
    const float* __restrict__ db, float* __restrict__ logits)
{
  __shared__ float4 Wl[ND];   // W_eff[d][0..3]
  __shared__ float4 bl;

  const int tid = threadIdx.x;
  const int blk = blockIdx.x;
  const int b = blk >> 4;                                   // 16 blocks/batch
  const int c = __builtin_amdgcn_readfirstlane(corpus[b]);  // uniform

  // stage W_eff into LDS (3 float4 per thread, coalesced)
  const float4* sW4 = (const float4*)sW;
  const float4* dA4 = ((const float4*)dA) + (size_t)c * ND;
#pragma unroll
  for (int k = 0; k < 3; ++k) {
    const int d = tid + k * 256;
    const float4 a = sW4[d];
    const float4 e = dA4[d];
    Wl[d] = make_float4(a.x + e.x, a.y + e.y, a.z + e.z, a.w + e.w);
  }
  if (tid == 0) {
    const float4 a = *(const float4*)sb;
    const float4 e = ((const float4*)db)[c];
    bl = make_float4(a.x + e.x, a.y + e.y, a.z + e.z, a.w + e.w);
  }
  __syncthreads();

  const int lane = tid & 63;
  const int grp  = lane >> 4;          // 4 groups per wave
  const int q    = lane & 15;          // lane within group
  const int gA   = blk * 32 + (tid >> 6) * 8 + grp * 2;  // token A
  const int gB   = gA + 1;                               // token B

  const float4* __restrict__ rowA =
      (const float4*)(embed + (size_t)words[gA] * ND);
  const float4* __restrict__ rowB =
      (const float4*)(embed + (size_t)words[gB] * ND);

  float a0 = 0.f, a1 = 0.f, a2 = 0.f, a3 = 0.f;
  float b0 = 0.f, b1 = 0.f, b2 = 0.f, b3 = 0.f;
#pragma unroll
  for (int i = 0; i < 12; ++i) {
    const float4 xa = rowA[i * 16 + q];
    const float4 xb = rowB[i * 16 + q];
    const float4 w0 = Wl[i * 64 + q * 4 + 0];
    const float4 w1 = Wl[i * 64 + q * 4 + 1];
    const float4 w2 = Wl[i * 64 + q * 4 + 2];
    const float4 w3 = Wl[i * 64 + q * 4 + 3];
    a0 = fmaf(xa.x, w0.x, a0); a1 = fmaf(xa.x, w0.y, a1);
    a2 = fmaf(xa.x, w0.z, a2); a3 = fmaf(xa.x, w0.w, a3);
    b0 = fmaf(xb.x, w0.x, b0); b1 = fmaf(xb.x, w0.y, b1);
    b2 = fmaf(xb.x, w0.z, b2); b3 = fmaf(xb.x, w0.w, b3);
    a0 = fmaf(xa.y, w1.x, a0); a1 = fmaf(xa.y, w1.y, a1);
    a2 = fmaf(xa.y, w1.z, a2); a3 = fmaf(xa.y, w1.w, a3);
    b0 = fmaf(xb.y, w1.x, b0); b1 = fmaf(xb.y, w1.y, b1);
    b2 = fmaf(xb.y, w1.z, b2); b3 = fmaf(xb.y, w1.w, b3);
    a0 = fmaf(xa.z, w2.x, a0); a1 = fmaf(xa.z, w2.y, a1);
    a2 = fmaf(xa.z, w2.z, a2); a3 = fmaf(xa.z, w2.w, a3);
    b0 = fmaf(xb.z, w2.x, b0); b1 = fmaf(xb.z, w2.y, b1);
    b2 = fmaf(xb.z, w2.z, b2); b3 = fmaf(xb.z, w2.w, b3);
    a0 = fmaf(xa.w, w3.x, a0); a1 = fmaf(xa.w, w3.y, a1);
    a2 = fmaf(xa.w, w3.z, a2); a3 = fmaf(xa.w, w3.w, a3);
    b0 = fmaf(xb.w, w3.x, b0); b1 = fmaf(xb.w, w3.y, b1);
    b2 = fmaf(xb.w, w3.z, b2); b3 = fmaf(xb.w, w3.w, b3);
  }

  // 16-lane group reduce (4 levels), both tokens
#pragma unroll
  for (int off = 8; off; off >>= 1) {
    a0 += __shfl_xor(a0, off); a1 += __shfl_xor(a1, off);
    a2 += __shfl_xor(a2, off); a3 += __shfl_xor(a3, off);
    b0 += __shfl_xor(b0, off); b1 += __shfl_xor(b1, off);
    b2 += __shfl_xor(b2, off); b3 += __shfl_xor(b3, off);
  }

  if (q < 2) {
    float s0 = (q == 0) ? a0 : b0;
    float s1 = (q == 0) ? a1 : b1;
    float s2 = (q == 0) ? a2 : b2;
    float s3 = (q == 0) ? a3 : b3;
    s0 += bl.x; s1 += bl.y; s2 += bl.z; s3 += bl.w;
    const float m = fmaxf(fmaxf(s0, s1), fmaxf(s2, s3));
    const float sum = __expf(s0 - m) + __expf(s1 - m) +
                      __expf(s2 - m) + __expf(s3 - m);
    const float lse = m + __logf(sum);
    ((float4*)logits)[gA + q] = make_float4(s0 - lse, s1 - lse, s2 - lse, s3 - lse);
  }
}

// ---------------------------------------------------------------------------
// Kernel 2: CRF chunk-parallel scan, base-2 domain, 512 threads/block.
// 64 blocks; 128 chunks x 4 steps (serial depth 4), 7-level LDS tree.
// Gold fused: 1 position/thread, trans/start/end staged in LDS.
// ---------------------------------------------------------------------------
__global__ __launch_bounds__(512) void crf_kernel(
    const int* __restrict__ words, const int* __restrict__ target,
    const float* __restrict__ trans, const float* __restrict__ start_s,
    const float* __restrict__ end_s, const float* __restrict__ logits,
    float* __restrict__ out)
{
  const int tid = threadIdx.x;
  const int b = blockIdx.x;
  const int c = tid >> 2;   // chunk 0..127
  const int a = tid & 3;    // basis row

  __shared__ float bufA[128][16];
  __shared__ float bufB[64][16];
  __shared__ float wg[8];
  __shared__ int   wc[8];
  __shared__ float sT[16], sS[4], sE[4];

  if (tid < 16) sT[tid] = trans[tid];
  if (tid < 4)  { sS[tid] = start_s[tid]; sE[tid] = end_s[tid]; }

  const float* lg = logits + (size_t)b * NS * NT;
  const int* wb = words + b * NS;
  const int* tb = target + b * NS;

  // ---- phase A inputs ----
  const int s_beg = 1 + c * 4;   // chunks cover s = 1..511
  float4 lv[4]; int wm[4];
#pragma unroll
  for (int q = 0; q < 4; ++q) {
    const int s = s_beg + q;
    const bool in = s < NS;
    wm[q] = in ? wb[s] : 0;
    lv[q] = in ? *(const float4*)(lg + s * 4) : make_float4(0.f, 0.f, 0.f, 0.f);
  }

  __syncthreads();   // sT/sS/sE ready

  // base-2 transition matrix in registers
  float T2[4][4];
#pragma unroll
  for (int i = 0; i < 4; ++i)
#pragma unroll
    for (int j = 0; j < 4; ++j) T2[i][j] = sT[i * 4 + j] * LOG2E;

  // ---- gold partial: position s = tid ----
  float gp = 0.f; int cp = 0;
  {
    const int s = tid;
    if (wb[s] != 0) {
      const int t = tb[s];
      gp += lg[s * 4 + t];
      if (s > 0) gp += sT[tb[s - 1] * 4 + t];
      ++cp;
    }
  }
#pragma unroll
  for (int off = 32; off; off >>= 1) {
    gp += __shfl_xor(gp, off);
    cp += __shfl_xor(cp, off);
  }
  if ((tid & 63) == 0) { wg[tid >> 6] = gp; wc[tid >> 6] = cp; }

  // ---- phase A: 4-step chunk recursion (base-2) ----
  float v0 = (a == 0) ? 0.f : NEG;
  float v1 = (a == 1) ? 0.f : NEG;
  float v2 = (a == 2) ? 0.f : NEG;
  float v3 = (a == 3) ? 0.f : NEG;
#pragma unroll
  for (int q = 0; q < 4; ++q) {
    if (wm[q] != 0) {
      const float4 l = lv[q];
      float t0, t1, t2, t3, m, sm;
      float n0, n1, n2, n3;
      t0 = v0 + T2[0][0]; t1 = v1 + T2[1][0]; t2 = v2 + T2[2][0]; t3 = v3 + T2[3][0];
      m = fmaxf(fmaxf(t0, t1), fmaxf(t2, t3));
      sm = exp2f(t0 - m) + exp2f(t1 - m) + exp2f(t2 - m) + exp2f(t3 - m);
      n0 = m + log2f(sm) + l.x * LOG2E;
      t0 = v0 + T2[0][1]; t1 = v1 + T2[1][1]; t2 = v2 + T2[2][1]; t3 = v3 + T2[3][1];
      m = fmaxf(fmaxf(t0, t1), fmaxf(t2, t3));
      sm = exp2f(t0 - m) + exp2f(t1 - m) + exp2f(t2 - m) + exp2f(t3 - m);
      n1 = m + log2f(sm) + l.y * LOG2E;
      t0 = v0 + T2[0][2]; t1 = v1 + T2[1][2]; t2 = v2 + T2[2][2]; t3 = v3 + T2[3][2];
      m = fmaxf(fmaxf(t0, t1), fmaxf(t2, t3));
      sm = exp2f(t0 - m) + exp2f(t1 - m) + exp2f(t2 - m) + exp2f(t3 - m);
      n2 = m + log2f(sm) + l.z * LOG2E;
      t0 = v0 + T2[0][3]; t1 = v1 + T2[1][3]; t2 = v2 + T2[2][3]; t3 = v3 + T2[3][3];
      m = fmaxf(fmaxf(t0, t1), fmaxf(t2, t3));
      sm = exp2f(t0 - m) + exp2f(t1 - m) + exp2f(t2 - m) + exp2f(t3 - m);
      n3 = m + log2f(sm) + l.w * LOG2E;
      v0 = n0; v1 = n1; v2 = n2; v3 = n3;
    }
  }
  bufA[c][a * 4 + 0] = v0;
  bufA[c][a * 4 + 1] = v1;
  bufA[c][a * 4 + 2] = v2;
  bufA[c][a * 4 + 3] = v3;

  // ---- phase B: 7-level pairwise tree (base-2) ----
  float* src = &bufA[0][0];
  float* dst = &bufB[0][0];
  for (int n = 128; n > 1; n >>= 1) {
    const int entries = (n >> 1) * 16;
    __syncthreads();
    for (int e = tid; e < entries; e += 512) {
      const int p = e >> 4;
      const int aa = (e >> 2) & 3;
      const int jj = e & 3;
      const float* C1 = src + (2 * p) * 16;
      const float* C2 = src + (2 * p + 1) * 16;
      const float t0 = C1[aa * 4 + 0] + C2[0 * 4 + jj];
      const float t1 = C1[aa * 4 + 1] + C2[1 * 4 + jj];
      const float t2 = C1[aa * 4 + 2] + C2[2 * 4 + jj];
      const float t3 = C1[aa * 4 + 3] + C2[3 * 4 + jj];
      const float m = fmaxf(fmaxf(t0, t1), fmaxf(t2, t3));
      dst[p * 16 + aa * 4 + jj] =
          m + log2f(exp2f(t0 - m) + exp2f(t1 - m) +
                    exp2f(t2 - m) + exp2f(t3 - m));
    }
    float* tmp = src; src = dst; dst = tmp;
  }
  __syncthreads();
  // result matrix is in *src (7 swaps from bufA -> bufB)

  if (tid == 0) {
    const float* C = src;
    const float4 l0 = *(const float4*)lg;
    const float a0 = (l0.x + sS[0]) * LOG2E;
    const float a1 = (l0.y + sS[1]) * LOG2E;
    const float a2 = (l0.z + sS[2]) * LOG2E;
    const float a3 = (l0.w + sS[3]) * LOG2E;
    float z[4];
#pragma unroll
    for (int j = 0; j < 4; ++j) {
      const float t0 = a0 + C[0 * 4 + j];
      const float t1 = a1 + C[1 * 4 + j];
      const float t2 = a2 + C[2 * 4 + j];
      const float t3 = a3 + C[3 * 4 + j];
      const float m = fmaxf(fmaxf(t0, t1), fmaxf(t2, t3));
      z[j] = m + log2f(exp2f(t0 - m) + exp2f(t1 - m) +
                       exp2f(t2 - m) + exp2f(t3 - m)) + sE[j] * LOG2E;
    }
    const float mz = fmaxf(fmaxf(z[0], z[1]), fmaxf(z[2], z[3]));
    const float norm = LN2 * (mz + log2f(exp2f(z[0] - mz) + exp2f(z[1] - mz) +
                                         exp2f(z[2] - mz) + exp2f(z[3] - mz)));

    float gold = wg[0] + wg[1] + wg[2] + wg[3] + wg[4] + wg[5] + wg[6] + wg[7];
    const int cnt = wc[0] + wc[1] + wc[2] + wc[3] + wc[4] + wc[5] + wc[6] + wc[7];
    const int last = (cnt - 1) > 0 ? (cnt - 1) : 0;
    gold += sS[tb[0]] + sE[tb[last]];
    out[b] = norm - gold;
  }
}

extern "C" void kernel_launch(void* const* d_in, const int* in_sizes, int n_in,
                              void* d_out, int out_size, void* d_ws, size_t ws_size,
                              hipStream_t stream) {
  const int*   words   = (const int*)d_in[0];
  const int*   target  = (const int*)d_in[1];
  const int*   corpus  = (const int*)d_in[2];
  const float* embed   = (const float*)d_in[3];
  const float* sW      = (const float*)d_in[4];
  const float* sb      = (const float*)d_in[5];
  const float* dA      = (const float*)d_in[6];
  const float* db      = (const float*)d_in[7];
  const float* trans   = (const float*)d_in[8];
  const float* start_s = (const float*)d_in[9];
  const float* end_s   = (const float*)d_in[10];
  float* out = (float*)d_out;
  float* logits = (float*)d_ws;   // NB*NS*NT floats = 512 KB

  logits_kernel<<<(NB * NS) / 32, 256, 0, stream>>>(words, corpus, embed, sW, sb, dA, db, logits);
  crf_kernel<<<NB, 512, 0, stream>>>(words, target, trans, start_s, end_s, logits, out);
}